// Round 1
// baseline (452.403 us; speedup 1.0000x reference)
//
#include <hip/hip_runtime.h>
#include <hip/hip_cooperative_groups.h>
#include <math.h>

typedef unsigned short u16;
typedef __attribute__((ext_vector_type(8))) short bf16x8;
typedef __attribute__((ext_vector_type(4))) float f32x4;

#define D_MODEL 256
#define T_SZ 1024
constexpr size_t S_ELT = (size_t)8192 * 256;
constexpr size_t MB = 1024 * 1024;

// workspace byte offsets (56MB footprint)
constexpr size_t OFF_QKV = 0;          // u16 [8192][768] (12MB, V region unused); later f overlays [0,16MB)
constexpr size_t OFF_ATTN = 12 * MB;   // u16 [8192][256] (4MB); later states_bf
constexpr size_t OFF_F = 0;            // u16 [8192][1024] (16MB)
constexpr size_t OFF_X = 16 * MB;      // f32 [8192][256] (8MB)
constexpr size_t OFF_COMB = 24 * MB;   // u16 [8192][768] (12MB); pr_bf + later ffn_in overlay head
constexpr size_t OFF_FB = 36 * MB;     // f32 [8192][256]: deltas
constexpr size_t OFF_H = 44 * MB;      // u16: vt (4MB, dead after attn) then h (8MB)
constexpr size_t OFF_XBF = 48 * MB;    // u16 x_bf (4MB)
constexpr size_t OFF_WB = 52 * MB;     // u16 weights (2.75MB)
constexpr size_t OFF_SCR1 = 55 * MB;           // f32 65536
constexpr size_t OFF_SCR2 = 55 * MB + 262144;  // f32 65536

// bf16 weight element offsets inside WB
constexpr int WB_INPROJ = 0;
constexpr int WB_OUTPROJ = 196608;
constexpr int WB_P2S = 262144;
constexpr int WB_S2P = 327680;
constexpr int WB_T1 = 393216;
constexpr int WB_T2 = 786432;
constexpr int WB_F1 = 917504;
constexpr int WB_F2 = 1179648;
constexpr int WB_TOTAL = 1441792;
constexpr int PR_TOTAL = 2097152;

__device__ __forceinline__ u16 f2bf(float f) {
  unsigned int u = __float_as_uint(f);
  u += 0x7fff + ((u >> 16) & 1);
  return (u16)(u >> 16);
}
__device__ __forceinline__ float bf2f(u16 s) {
  return __uint_as_float(((unsigned int)s) << 16);
}

// async global -> LDS, 16B per lane; LDS dst is wave-uniform base + lane*16B.
__device__ __forceinline__ void glds16(const u16* g, u16* l) {
  __builtin_amdgcn_global_load_lds(
      (const __attribute__((address_space(1))) void*)g,
      (__attribute__((address_space(3))) void*)l, 16, 0, 0);
}

// ---------------------------------------------------------------------------
// weight + parallel_repr fp32 -> bf16 conversion (single kernel)
// ---------------------------------------------------------------------------
__global__ __launch_bounds__(256)
void wconv_kernel(const float* w0, const float* w1, const float* w2,
                  const float* w3, const float* w4, const float* w5,
                  const float* w6, const float* w7, const float* pr,
                  u16* __restrict__ wb, u16* __restrict__ prb) {
  const int idx4 = (blockIdx.x * 256 + threadIdx.x) * 4;
  if (idx4 < WB_TOTAL) {
    const int offs[9] = {WB_INPROJ, WB_OUTPROJ, WB_P2S,  WB_S2P, WB_T1,
                         WB_T2,     WB_F1,      WB_F2,   WB_TOTAL};
    const float* srcs[8] = {w0, w1, w2, w3, w4, w5, w6, w7};
    int seg = 0;
    while (idx4 >= offs[seg + 1]) ++seg;
    float4 v = *(const float4*)(srcs[seg] + (idx4 - offs[seg]));
    unsigned int lo = (unsigned int)f2bf(v.x) | ((unsigned int)f2bf(v.y) << 16);
    unsigned int hi = (unsigned int)f2bf(v.z) | ((unsigned int)f2bf(v.w) << 16);
    *(uint2*)(wb + idx4) = make_uint2(lo, hi);
  } else {
    const int i4 = idx4 - WB_TOTAL;
    if (i4 < PR_TOTAL) {
      float4 v = *(const float4*)(pr + i4);
      unsigned int lo = (unsigned int)f2bf(v.x) | ((unsigned int)f2bf(v.y) << 16);
      unsigned int hi = (unsigned int)f2bf(v.z) | ((unsigned int)f2bf(v.w) << 16);
      *(uint2*)(prb + i4) = make_uint2(lo, hi);
    }
  }
}

// ---------------------------------------------------------------------------
// bf16 MFMA GEMM: async global_load_lds staging into fragment-ordered LDS.
// BK=64 (two MFMA sub-steps per barrier pair).
// VSPLIT (in_proj): cols >=512 (V) are written transposed to vt instead.
// ---------------------------------------------------------------------------
enum { EPI_NONE = 0, EPI_GELU = 1, EPI_ADDSCALE = 2 };

template <int EPI, int BM, int BN, bool OUTBF, bool VSPLIT>
__global__ __launch_bounds__(256, 4)
void mgemm(const u16* __restrict__ A, int lda,
           const u16* __restrict__ Wb, int K, const float* __restrict__ bias,
           void* __restrict__ Cv, int ldc, int col_off,
           const float* __restrict__ addsrc, u16* __restrict__ vt) {
  __shared__ u16 As[BM * 64];
  __shared__ u16 Bs[BN * 64];
  const int tid = threadIdx.x;
  const int w = tid >> 6, lane = tid & 63;
  const int ln = lane & 15, quad = lane >> 4;
  const int m0 = blockIdx.x * BM;
  const int n0 = blockIdx.y * BN;
  constexpr int MT = (BM == 128) ? 2 : 1;  // wave rows = 4 waves x (MT*16)
  const int wm = w * (MT * 16);
  constexpr int wn = 0;
  constexpr int APW = BM / 64;  // A 16-row groups per wave per sub-step
  constexpr int BPW = BN / 64;

  f32x4 acc[MT][4] = {};

  const int grow = lane >> 2;      // row within 16-row group
  const int gk8 = (lane & 3) * 8;  // k element offset

  for (int k0 = 0; k0 < K; k0 += 64) {
#pragma unroll
    for (int s = 0; s < 2; ++s) {
#pragma unroll
      for (int p = 0; p < APW; ++p) {
        const int g = w * APW + p;
        glds16(A + (size_t)(m0 + g * 16 + grow) * lda + k0 + s * 32 + gk8,
               As + s * BM * 32 + g * 512);
      }
#pragma unroll
      for (int p = 0; p < BPW; ++p) {
        const int g = w * BPW + p;
        glds16(Wb + (size_t)(n0 + g * 16 + grow) * K + k0 + s * 32 + gk8,
               Bs + s * BN * 32 + g * 512);
      }
    }
    __syncthreads();  // drains vmcnt -> LDS valid
#pragma unroll
    for (int s = 0; s < 2; ++s) {
      const u16* abase = As + s * BM * 32 + (wm >> 4) * 512 + ln * 32 + quad * 8;
      const u16* bbase = Bs + s * BN * 32 + ln * 32 + quad * 8;
      bf16x8 af[MT], bv[4];
#pragma unroll
      for (int i = 0; i < MT; ++i) af[i] = *(const bf16x8*)(abase + i * 512);
#pragma unroll
      for (int j = 0; j < 4; ++j) bv[j] = *(const bf16x8*)(bbase + j * 512);
#pragma unroll
      for (int i = 0; i < MT; ++i)
#pragma unroll
        for (int j = 0; j < 4; ++j)
          acc[i][j] = __builtin_amdgcn_mfma_f32_16x16x32_bf16(af[i], bv[j],
                                                              acc[i][j], 0, 0, 0);
    }
    __syncthreads();  // protect LDS reuse next iter
  }

#pragma unroll
  for (int i = 0; i < MT; ++i)
#pragma unroll
    for (int j = 0; j < 4; ++j) {
      const int col = n0 + wn + j * 16 + ln;
      const float bsv = bias[col];
      const int row0 = m0 + wm + i * 16 + quad * 4;
      float vals[4];
#pragma unroll
      for (int r = 0; r < 4; ++r) {
        float v = acc[i][j][r] + bsv;
        if (EPI == EPI_GELU) v = 0.5f * v * (1.0f + erff(v * 0.70710678f));
        if (EPI == EPI_ADDSCALE)
          v = addsrc[(size_t)(row0 + r) * 256 + col] + 0.3f * v;
        vals[r] = v;
      }
      if (VSPLIT && col >= 512) {
        // V: write transposed vt[(b*256 + (col-512))][t], 4 consecutive t
        ushort4 pk;
        pk.x = f2bf(vals[0]); pk.y = f2bf(vals[1]);
        pk.z = f2bf(vals[2]); pk.w = f2bf(vals[3]);
        *(ushort4*)(vt + (size_t)((row0 >> 10) * 256 + (col - 512)) * T_SZ +
                    (row0 & 1023)) = pk;
      } else if (OUTBF) {
#pragma unroll
        for (int r = 0; r < 4; ++r)
          ((u16*)Cv)[(size_t)(row0 + r) * ldc + col_off + col] = f2bf(vals[r]);
      } else {
#pragma unroll
        for (int r = 0; r < 4; ++r)
          ((float*)Cv)[(size_t)(row0 + r) * ldc + col_off + col] = vals[r];
      }
    }
}

// ---------------------------------------------------------------------------
// Fused GEMM (+add) + LayerNorm epilogue. BM=64, BN=256 = full row width per
// block, so each wave owns 16 complete rows and the LN reduction is wave-local
// (shfl_xor over the 16-lane ln group; quad is row-parallel). Writes LN output
// fp32 (+optional bf16 mirror). v = addsrc + (A@W^T + bias); y = LN(v).
// ---------------------------------------------------------------------------
template <bool WRITE_BF>
__global__ __launch_bounds__(256, 2)
void mgemm_ln(const u16* __restrict__ A, const u16* __restrict__ Wb, int K,
              const float* __restrict__ bias, const float* __restrict__ addsrc,
              const float* __restrict__ g, const float* __restrict__ bb,
              float* __restrict__ outf, u16* __restrict__ outbf) {
  __shared__ u16 As[64 * 64];    // 8KB
  __shared__ u16 Bs[256 * 64];   // 32KB
  const int tid = threadIdx.x;
  const int w = tid >> 6, lane = tid & 63;
  const int ln = lane & 15, quad = lane >> 4;
  const int m0 = blockIdx.x * 64;
  const int grow = lane >> 2;
  const int gk8 = (lane & 3) * 8;

  f32x4 acc[16] = {};

  for (int k0 = 0; k0 < K; k0 += 64) {
#pragma unroll
    for (int s = 0; s < 2; ++s) {
      glds16(A + (size_t)(m0 + w * 16 + grow) * K + k0 + s * 32 + gk8,
             As + s * 2048 + w * 512);
#pragma unroll
      for (int p = 0; p < 4; ++p) {
        const int gg = w * 4 + p;
        glds16(Wb + (size_t)(gg * 16 + grow) * K + k0 + s * 32 + gk8,
               Bs + s * 8192 + gg * 512);
      }
    }
    __syncthreads();
#pragma unroll
    for (int s = 0; s < 2; ++s) {
      const u16* abase = As + s * 2048 + w * 512 + ln * 32 + quad * 8;
      const u16* bbase = Bs + s * 8192 + ln * 32 + quad * 8;
      bf16x8 af = *(const bf16x8*)abase;
#pragma unroll
      for (int j = 0; j < 16; ++j) {
        bf16x8 bv = *(const bf16x8*)(bbase + j * 512);
        acc[j] = __builtin_amdgcn_mfma_f32_16x16x32_bf16(af, bv, acc[j], 0, 0, 0);
      }
    }
    __syncthreads();
  }

  const int row0 = m0 + w * 16 + quad * 4;
  float s1[4] = {}, s2[4] = {};
#pragma unroll
  for (int j = 0; j < 16; ++j) {
    const int col = j * 16 + ln;
    const float bsv = bias[col];
#pragma unroll
    for (int r = 0; r < 4; ++r) {
      float v = acc[j][r] + bsv + addsrc[(size_t)(row0 + r) * 256 + col];
      acc[j][r] = v;
      s1[r] += v;
      s2[r] += v * v;
    }
  }
  // reduce over the 16 ln lanes (same quad => same rows on every lane)
#pragma unroll
  for (int r = 0; r < 4; ++r) {
#pragma unroll
    for (int o = 8; o > 0; o >>= 1) {
      s1[r] += __shfl_xor(s1[r], o);
      s2[r] += __shfl_xor(s2[r], o);
    }
  }
  float mean[4], inv[4];
#pragma unroll
  for (int r = 0; r < 4; ++r) {
    mean[r] = s1[r] * (1.f / 256.f);
    float var = s2[r] * (1.f / 256.f) - mean[r] * mean[r];
    inv[r] = rsqrtf(var + 1e-5f);
  }
#pragma unroll
  for (int j = 0; j < 16; ++j) {
    const int col = j * 16 + ln;
    const float gc = g[col], bc = bb[col];
#pragma unroll
    for (int r = 0; r < 4; ++r) {
      const float y = (acc[j][r] - mean[r]) * inv[r] * gc + bc;
      outf[(size_t)(row0 + r) * 256 + col] = y;
      if (WRITE_BF) outbf[(size_t)(row0 + r) * 256 + col] = f2bf(y);
    }
  }
}

// ---------------------------------------------------------------------------
// Barrier-free MFMA flash attention (one wave = 16 q rows, paired balance).
// ---------------------------------------------------------------------------
__global__ __launch_bounds__(256)
void attn_flash(const u16* __restrict__ qkv, const u16* __restrict__ vt,
                u16* __restrict__ outp) {
  __shared__ u16 Ps[4][16][72];
  const int tid = threadIdx.x;
  const int w = tid >> 6, lane = tid & 63;
  const int ln = lane & 15, quad = lane >> 4, kq8 = quad * 8;
  const int wu = blockIdx.x * 4 + w;
  const int bh = wu >> 6, s = wu & 63;
  const int qt = (s & 1) ? (63 - (s >> 1)) : (s >> 1);
  const int q0 = qt * 16;
  const int b = bh >> 2, h = bh & 3;
  const u16* base = qkv + (size_t)b * T_SZ * 768;
  const u16* vbase = vt + (size_t)bh * 64 * T_SZ;

  bf16x8 qf[2];
#pragma unroll
  for (int ks = 0; ks < 2; ++ks)
    qf[ks] = *(const bf16x8*)(base + (size_t)(q0 + ln) * 768 + h * 64 +
                              ks * 32 + kq8);
  const short ob = (short)0x3F80;
  const bf16x8 ones = {ob, ob, ob, ob, ob, ob, ob, ob};

  f32x4 O[4] = {};
  f32x4 l_acc = {};
  const int ntiles = (qt >> 2) + 1;
  for (int jt = 0; jt < ntiles; ++jt) {
    const int c0 = jt * 64;
    f32x4 sv[4] = {};
#pragma unroll
    for (int ks = 0; ks < 2; ++ks)
#pragma unroll
      for (int j = 0; j < 4; ++j) {
        bf16x8 kf = *(const bf16x8*)(base + (size_t)(c0 + j * 16 + ln) * 768 +
                                     256 + h * 64 + ks * 32 + kq8);
        sv[j] = __builtin_amdgcn_mfma_f32_16x16x32_bf16(qf[ks], kf, sv[j], 0, 0, 0);
      }
    const bool need_mask = (c0 + 63 > q0);
#pragma unroll
    for (int j = 0; j < 4; ++j)
#pragma unroll
      for (int r = 0; r < 4; ++r) {
        float p = __expf(sv[j][r] * 0.125f);
        if (need_mask && (c0 + j * 16 + ln > q0 + quad * 4 + r)) p = 0.f;
        Ps[w][quad * 4 + r][j * 16 + ln] = f2bf(p);
      }
#pragma unroll
    for (int ks = 0; ks < 2; ++ks) {
      bf16x8 pf = *(const bf16x8*)&Ps[w][ln][ks * 32 + kq8];
      l_acc = __builtin_amdgcn_mfma_f32_16x16x32_bf16(pf, ones, l_acc, 0, 0, 0);
#pragma unroll
      for (int j = 0; j < 4; ++j) {
        bf16x8 vf = *(const bf16x8*)(vbase + (size_t)(j * 16 + ln) * T_SZ +
                                     c0 + ks * 32 + kq8);
        O[j] = __builtin_amdgcn_mfma_f32_16x16x32_bf16(pf, vf, O[j], 0, 0, 0);
      }
    }
  }
  u16* op = outp + (size_t)b * T_SZ * 256;
#pragma unroll
  for (int r = 0; r < 4; ++r) {
    const float inv = 1.f / l_acc[r];
#pragma unroll
    for (int j = 0; j < 4; ++j)
      op[(size_t)(q0 + quad * 4 + r) * 256 + h * 64 + j * 16 + ln] =
          f2bf(O[j][r] * inv);
  }
}

// ---------------------------------------------------------------------------
// block reduction helpers (fp32)
// ---------------------------------------------------------------------------
__device__ __forceinline__ void block_reduce_2(float& a, float& q, float* tmp) {
#pragma unroll
  for (int o = 32; o > 0; o >>= 1) {
    a += __shfl_down(a, o);
    q += __shfl_down(q, o);
  }
  const int lane = threadIdx.x & 63, wid = threadIdx.x >> 6;
  if (lane == 0) { tmp[wid] = a; tmp[4 + wid] = q; }
  __syncthreads();
  a = tmp[0] + tmp[1] + tmp[2] + tmp[3];
  q = tmp[4] + tmp[5] + tmp[6] + tmp[7];
  __syncthreads();
}

__device__ __forceinline__ float ln_finish(float v, float s1, float s2,
                                           float g, float bb) {
  float mean = s1 * (1.f / 256.f);
  float var = s2 * (1.f / 256.f) - mean * mean;
  return (v - mean) * rsqrtf(var + 1e-5f) * g + bb;
}

// ---------------------------------------------------------------------------
// Cooperative fused depthwise conv (window 8) + full EMA (3 phases in one
// kernel; local EMA values stay in registers across the grid syncs).
// grid = 256 blocks (b,ch), block = 256 (d).
// ---------------------------------------------------------------------------
__global__ __launch_bounds__(256)
void emaconv_coop(const float* __restrict__ x, const float* __restrict__ cw,
                  const float* __restrict__ cb, u16* __restrict__ comb,
                  float* __restrict__ scr, float* __restrict__ fts) {
  cooperative_groups::grid_group grid = cooperative_groups::this_grid();
  const int bc = blockIdx.x;
  const int b = bc >> 5, ch = bc & 31;
  const int d = threadIdx.x;
  const int t0 = ch * 32;
  float wreg[8];
#pragma unroll
  for (int j = 0; j < 8; ++j) wreg[j] = cw[d * 8 + j];
  const float bias = cb[d];
  float xw[8];
#pragma unroll
  for (int j = 0; j < 7; ++j) {
    const int ts = t0 - 7 + j;
    xw[j] = (ts >= 0) ? x[(size_t)(b * T_SZ + ts) * 256 + d] : 0.f;
  }
  float lreg[32];
  float c = 0.f;
#pragma unroll
  for (int tl = 0; tl < 32; ++tl) {
    const size_t row = (size_t)(b * T_SZ + t0 + tl);
    xw[7] = x[row * 256 + d];
    float conv = bias;
#pragma unroll
    for (int j = 0; j < 8; ++j) conv = fmaf(xw[j], wreg[j], conv);
    c = 0.9f * c + 0.1f * xw[7];
    lreg[tl] = c;
    comb[row * 768 + 256 + d] = f2bf(conv);
#pragma unroll
    for (int j = 0; j < 7; ++j) xw[j] = xw[j + 1];
  }
  scr[(size_t)bc * 256 + d] = c;
  grid.sync();
  // phase b: per-batch exclusive scan of chunk EMAs (8 active blocks)
  if (bc < 8) {
    const float q32 = 0.03433683820292512f;  // 0.9^32
    float carry = 0.f;
    for (int chh = 0; chh < 32; ++chh) {
      const size_t idx = (size_t)(bc * 32 + chh) * 256 + d;
      float e = scr[idx];
      scr[idx] = carry;
      carry = e + q32 * carry;
    }
  }
  grid.sync();
  // phase c: apply carry to register-held local EMAs
  const float carry = scr[(size_t)bc * 256 + d];
  float pw = 0.9f;
  float ylast = 0.f;
#pragma unroll
  for (int tl = 0; tl < 32; ++tl) {
    const size_t row = (size_t)(b * T_SZ + t0 + tl);
    const float y = fmaf(pw, carry, lreg[tl]);
    comb[row * 768 + 512 + d] = f2bf(y);
    pw *= 0.9f;
    ylast = y;
  }
  if (ch == 31) fts[b * 256 + d] = ylast;
}

// ---------------------------------------------------------------------------
// Cooperative fused cumsum + LN3 (+LN4 on the last row). Chunk cumsums stay
// in registers; only the 8KB/batch chunk totals go through global memory.
// grid = 256 blocks (b,ch), block = 256 (d).
// ---------------------------------------------------------------------------
__global__ __launch_bounds__(256)
void csln_coop(const float* __restrict__ deltas, const float* __restrict__ seq,
               const float* __restrict__ g3, const float* __restrict__ b3,
               const float* __restrict__ g4, const float* __restrict__ b4,
               float* __restrict__ scr, u16* __restrict__ st,
               float* __restrict__ fss) {
  cooperative_groups::grid_group grid = cooperative_groups::this_grid();
  __shared__ float tmp[8];
  const int bc = blockIdx.x;
  const int b = bc >> 5, ch = bc & 31;
  const int d = threadIdx.x;
  const int t0 = ch * 32;
  float cum[32];
  float c = 0.f;
#pragma unroll
  for (int tl = 0; tl < 32; ++tl) {
    c += deltas[(size_t)(b * T_SZ + t0 + tl) * 256 + d];
    cum[tl] = c;
  }
  scr[(size_t)bc * 256 + d] = c;
  grid.sync();
  if (bc < 8) {
    float carry = 0.f;
    for (int chh = 0; chh < 32; ++chh) {
      const size_t idx = (size_t)(bc * 32 + chh) * 256 + d;
      float e = scr[idx];
      scr[idx] = carry;
      carry += e;
    }
  }
  grid.sync();
  const float carry = scr[(size_t)bc * 256 + d];
  const float sv = seq[b * 256 + d];
  const float gg3 = g3[d], bb3 = b3[d];
#pragma unroll
  for (int tl = 0; tl < 32; ++tl) {
    const size_t row = (size_t)(b * T_SZ + t0 + tl);
    float v = sv + 0.5f * (cum[tl] + carry);
    float a = v, q = v * v;
    block_reduce_2(a, q, tmp);
    const float y = ln_finish(v, a, q, gg3, bb3);
    st[row * 256 + d] = f2bf(y);
    if (ch == 31 && tl == 31) {  // block-uniform branch: LN4 of states[:, -1]
      float a2 = y, q2 = y * y;
      block_reduce_2(a2, q2, tmp);
      fss[b * 256 + d] = ln_finish(y, a2, q2, g4[d], b4[d]);
    }
  }
}

// ---------------------------------------------------------------------------
extern "C" void kernel_launch(void* const* d_in, const int* in_sizes, int n_in,
                              void* d_out, int out_size, void* d_ws,
                              size_t ws_size, hipStream_t stream) {
  (void)in_sizes; (void)n_in; (void)out_size; (void)ws_size;
  const float* parallel_repr = (const float*)d_in[0];
  const float* sequential_state = (const float*)d_in[1];
  const float* in_proj_b = (const float*)d_in[4];
  const float* out_proj_b = (const float*)d_in[6];
  const float* conv_w = (const float*)d_in[7];
  const float* conv_b = (const float*)d_in[8];
  const float* p2s_b = (const float*)d_in[10];
  const float* s2p_b = (const float*)d_in[12];
  const float* trans_b1 = (const float*)d_in[14];
  const float* trans_b2 = (const float*)d_in[16];
  const float* ffn_b1 = (const float*)d_in[18];
  const float* ffn_b2 = (const float*)d_in[20];
  const float* ln1_s = (const float*)d_in[21];
  const float* ln1_b = (const float*)d_in[22];
  const float* ln2_s = (const float*)d_in[23];
  const float* ln2_b = (const float*)d_in[24];
  const float* ln3_s = (const float*)d_in[25];
  const float* ln3_b = (const float*)d_in[26];
  const float* ln4_s = (const float*)d_in[27];
  const float* ln4_b = (const float*)d_in[28];

  char* ws = (char*)d_ws;
  u16* qkv_bf = (u16*)(ws + OFF_QKV);
  u16* attn_bf = (u16*)(ws + OFF_ATTN);
  u16* states_bf = (u16*)(ws + OFF_ATTN);
  u16* f_bf = (u16*)(ws + OFF_F);
  float* x = (float*)(ws + OFF_X);
  u16* comb = (u16*)(ws + OFF_COMB);
  u16* pr_bf = (u16*)(ws + OFF_COMB);  // dead before comb is written
  u16* ffn_in = (u16*)(ws + OFF_COMB); // overlay after comb consumed
  float* fbuf = (float*)(ws + OFF_FB);
  u16* vt = (u16*)(ws + OFF_H);        // dead before h is written
  u16* h_bf = (u16*)(ws + OFF_H);
  u16* x_bf = (u16*)(ws + OFF_XBF);
  u16* wb = (u16*)(ws + OFF_WB);
  float* scr1 = (float*)(ws + OFF_SCR1);
  float* scr2 = (float*)(ws + OFF_SCR2);
  float* out = (float*)d_out;
  float* out_fss = out + S_ELT;
  float* out_fts = out + S_ELT + 2048;

  const dim3 blk(256);

  // 0. weights + parallel_repr -> bf16
  wconv_kernel<<<3456, blk, 0, stream>>>(
      (const float*)d_in[3], (const float*)d_in[5], (const float*)d_in[9],
      (const float*)d_in[11], (const float*)d_in[13], (const float*)d_in[15],
      (const float*)d_in[17], (const float*)d_in[19], parallel_repr, wb, pr_bf);
  // 1. qkv = PR @ in_proj^T + b; V columns written transposed to vt
  mgemm<EPI_NONE, 128, 64, true, true><<<dim3(64, 12), blk, 0, stream>>>(
      pr_bf, 256, wb + WB_INPROJ, 256, in_proj_b, qkv_bf, 768, 0, nullptr, vt);
  // 2. attention (barrier-free)
  attn_flash<<<512, blk, 0, stream>>>(qkv_bf, vt, attn_bf);
  // 3. x = LN1(PR + attn @ out_proj^T + b), fused GEMM+LN -> x fp32 + x_bf
  mgemm_ln<true><<<128, blk, 0, stream>>>(
      attn_bf, wb + WB_OUTPROJ, 256, out_proj_b, parallel_repr, ln1_s, ln1_b,
      x, x_bf);
  // 4. fused conv + full EMA (cooperative, 3 phases) -> comb[:,256:768], fts
  {
    void* eargs[] = {(void*)&x, (void*)&conv_w, (void*)&conv_b, (void*)&comb,
                     (void*)&scr1, (void*)&out_fts};
    hipLaunchCooperativeKernel(reinterpret_cast<void*>(emaconv_coop),
                               dim3(256), blk, eargs, 0, stream);
  }
  // 5. comb[:,0:256] = x + 0.3*(x @ p2s^T + b)
  mgemm<EPI_ADDSCALE, 64, 64, true, false><<<dim3(128, 4), blk, 0, stream>>>(
      x_bf, 256, wb + WB_P2S, 256, p2s_b, comb, 768, 0, x, nullptr);
  // 6. h = gelu(comb @ t1^T + b1)
  mgemm<EPI_GELU, 128, 64, true, false><<<dim3(64, 8), blk, 0, stream>>>(
      comb, 768, wb + WB_T1, 768, trans_b1, h_bf, 512, 0, nullptr, nullptr);
  // 7. deltas = h @ t2^T + b2 -> fbuf (fp32)
  mgemm<EPI_NONE, 64, 64, false, false><<<dim3(128, 4), blk, 0, stream>>>(
      h_bf, 512, wb + WB_T2, 512, trans_b2, fbuf, 256, 0, nullptr, nullptr);
  // 8. fused cumsum + LN3 + LN4 (cooperative) -> states_bf, fss
  {
    void* cargs[] = {(void*)&fbuf, (void*)&sequential_state, (void*)&ln3_s,
                     (void*)&ln3_b, (void*)&ln4_s, (void*)&ln4_b,
                     (void*)&scr2, (void*)&states_bf, (void*)&out_fss};
    hipLaunchCooperativeKernel(reinterpret_cast<void*>(csln_coop),
                               dim3(256), blk, cargs, 0, stream);
  }
  // 9. ffn_in = x + 0.3*(states @ s2p^T + b)
  mgemm<EPI_ADDSCALE, 64, 64, true, false><<<dim3(128, 4), blk, 0, stream>>>(
      states_bf, 256, wb + WB_S2P, 256, s2p_b, ffn_in, 256, 0, x, nullptr);
  // 10. f = gelu(ffn_in @ ffn1^T + b1)
  mgemm<EPI_GELU, 128, 64, true, false><<<dim3(64, 16), blk, 0, stream>>>(
      ffn_in, 256, wb + WB_F1, 256, ffn_b1, f_bf, 1024, 0, nullptr, nullptr);
  // 11. out = LN2(x + f @ ffn2^T + b2), fused GEMM+LN
  mgemm_ln<false><<<128, blk, 0, stream>>>(
      f_bf, wb + WB_F2, 1024, ffn_b2, x, ln2_s, ln2_b, out, nullptr);
}

// Round 2
// 260.254 us; speedup vs baseline: 1.7383x; 1.7383x over previous
//
#include <hip/hip_runtime.h>
#include <math.h>

typedef unsigned short u16;
typedef __attribute__((ext_vector_type(8))) short bf16x8;
typedef __attribute__((ext_vector_type(4))) float f32x4;

#define D_MODEL 256
#define T_SZ 1024
constexpr size_t S_ELT = (size_t)8192 * 256;
constexpr size_t MB = 1024 * 1024;

// workspace byte offsets (56MB footprint)
constexpr size_t OFF_QKV = 0;          // u16 [8192][768] (12MB, V region unused); later f overlays [0,16MB)
constexpr size_t OFF_ATTN = 12 * MB;   // u16 [8192][256] (4MB); later states_bf
constexpr size_t OFF_F = 0;            // u16 [8192][1024] (16MB)
constexpr size_t OFF_X = 16 * MB;      // f32 [8192][256] (8MB)
constexpr size_t OFF_COMB = 24 * MB;   // u16 [8192][768] (12MB); pr_bf + later ffn_in overlay head
constexpr size_t OFF_FB = 36 * MB;     // f32 [8192][256]: deltas
constexpr size_t OFF_H = 44 * MB;      // u16: vt (4MB, dead after attn) then h (8MB)
constexpr size_t OFF_XBF = 48 * MB;    // u16 x_bf (4MB)
constexpr size_t OFF_WB = 52 * MB;     // u16 weights (2.75MB)
constexpr size_t OFF_SCR1 = 55 * MB;           // f32 65536
constexpr size_t OFF_SCR2 = 55 * MB + 262144;  // f32 65536

// bf16 weight element offsets inside WB
constexpr int WB_INPROJ = 0;
constexpr int WB_OUTPROJ = 196608;
constexpr int WB_P2S = 262144;
constexpr int WB_S2P = 327680;
constexpr int WB_T1 = 393216;
constexpr int WB_T2 = 786432;
constexpr int WB_F1 = 917504;
constexpr int WB_F2 = 1179648;
constexpr int WB_TOTAL = 1441792;
constexpr int PR_TOTAL = 2097152;

__device__ __forceinline__ u16 f2bf(float f) {
  unsigned int u = __float_as_uint(f);
  u += 0x7fff + ((u >> 16) & 1);
  return (u16)(u >> 16);
}
__device__ __forceinline__ float bf2f(u16 s) {
  return __uint_as_float(((unsigned int)s) << 16);
}

// async global -> LDS, 16B per lane; LDS dst is wave-uniform base + lane*16B.
__device__ __forceinline__ void glds16(const u16* g, u16* l) {
  __builtin_amdgcn_global_load_lds(
      (const __attribute__((address_space(1))) void*)g,
      (__attribute__((address_space(3))) void*)l, 16, 0, 0);
}

// ---------------------------------------------------------------------------
// weight + parallel_repr fp32 -> bf16 conversion (single kernel)
// ---------------------------------------------------------------------------
__global__ __launch_bounds__(256)
void wconv_kernel(const float* w0, const float* w1, const float* w2,
                  const float* w3, const float* w4, const float* w5,
                  const float* w6, const float* w7, const float* pr,
                  u16* __restrict__ wb, u16* __restrict__ prb) {
  const int idx4 = (blockIdx.x * 256 + threadIdx.x) * 4;
  if (idx4 < WB_TOTAL) {
    const int offs[9] = {WB_INPROJ, WB_OUTPROJ, WB_P2S,  WB_S2P, WB_T1,
                         WB_T2,     WB_F1,      WB_F2,   WB_TOTAL};
    const float* srcs[8] = {w0, w1, w2, w3, w4, w5, w6, w7};
    int seg = 0;
    while (idx4 >= offs[seg + 1]) ++seg;
    float4 v = *(const float4*)(srcs[seg] + (idx4 - offs[seg]));
    unsigned int lo = (unsigned int)f2bf(v.x) | ((unsigned int)f2bf(v.y) << 16);
    unsigned int hi = (unsigned int)f2bf(v.z) | ((unsigned int)f2bf(v.w) << 16);
    *(uint2*)(wb + idx4) = make_uint2(lo, hi);
  } else {
    const int i4 = idx4 - WB_TOTAL;
    if (i4 < PR_TOTAL) {
      float4 v = *(const float4*)(pr + i4);
      unsigned int lo = (unsigned int)f2bf(v.x) | ((unsigned int)f2bf(v.y) << 16);
      unsigned int hi = (unsigned int)f2bf(v.z) | ((unsigned int)f2bf(v.w) << 16);
      *(uint2*)(prb + i4) = make_uint2(lo, hi);
    }
  }
}

// ---------------------------------------------------------------------------
// bf16 MFMA GEMM: async global_load_lds staging into fragment-ordered LDS.
// BK=64 (two MFMA sub-steps per barrier pair).
// VSPLIT (in_proj): cols >=512 (V) are written transposed to vt instead.
// ---------------------------------------------------------------------------
enum { EPI_NONE = 0, EPI_GELU = 1, EPI_ADDSCALE = 2 };

template <int EPI, int BM, int BN, bool OUTBF, bool VSPLIT>
__global__ __launch_bounds__(256, 4)
void mgemm(const u16* __restrict__ A, int lda,
           const u16* __restrict__ Wb, int K, const float* __restrict__ bias,
           void* __restrict__ Cv, int ldc, int col_off,
           const float* __restrict__ addsrc, u16* __restrict__ vt) {
  __shared__ u16 As[BM * 64];
  __shared__ u16 Bs[BN * 64];
  const int tid = threadIdx.x;
  const int w = tid >> 6, lane = tid & 63;
  const int ln = lane & 15, quad = lane >> 4;
  const int m0 = blockIdx.x * BM;
  const int n0 = blockIdx.y * BN;
  constexpr int MT = (BM == 128) ? 2 : 1;  // wave rows = 4 waves x (MT*16)
  const int wm = w * (MT * 16);
  constexpr int wn = 0;
  constexpr int APW = BM / 64;  // A 16-row groups per wave per sub-step
  constexpr int BPW = BN / 64;

  f32x4 acc[MT][4] = {};

  const int grow = lane >> 2;      // row within 16-row group
  const int gk8 = (lane & 3) * 8;  // k element offset

  for (int k0 = 0; k0 < K; k0 += 64) {
#pragma unroll
    for (int s = 0; s < 2; ++s) {
#pragma unroll
      for (int p = 0; p < APW; ++p) {
        const int g = w * APW + p;
        glds16(A + (size_t)(m0 + g * 16 + grow) * lda + k0 + s * 32 + gk8,
               As + s * BM * 32 + g * 512);
      }
#pragma unroll
      for (int p = 0; p < BPW; ++p) {
        const int g = w * BPW + p;
        glds16(Wb + (size_t)(n0 + g * 16 + grow) * K + k0 + s * 32 + gk8,
               Bs + s * BN * 32 + g * 512);
      }
    }
    __syncthreads();  // drains vmcnt -> LDS valid
#pragma unroll
    for (int s = 0; s < 2; ++s) {
      const u16* abase = As + s * BM * 32 + (wm >> 4) * 512 + ln * 32 + quad * 8;
      const u16* bbase = Bs + s * BN * 32 + ln * 32 + quad * 8;
      bf16x8 af[MT], bv[4];
#pragma unroll
      for (int i = 0; i < MT; ++i) af[i] = *(const bf16x8*)(abase + i * 512);
#pragma unroll
      for (int j = 0; j < 4; ++j) bv[j] = *(const bf16x8*)(bbase + j * 512);
#pragma unroll
      for (int i = 0; i < MT; ++i)
#pragma unroll
        for (int j = 0; j < 4; ++j)
          acc[i][j] = __builtin_amdgcn_mfma_f32_16x16x32_bf16(af[i], bv[j],
                                                              acc[i][j], 0, 0, 0);
    }
    __syncthreads();  // protect LDS reuse next iter
  }

#pragma unroll
  for (int i = 0; i < MT; ++i)
#pragma unroll
    for (int j = 0; j < 4; ++j) {
      const int col = n0 + wn + j * 16 + ln;
      const float bsv = bias[col];
      const int row0 = m0 + wm + i * 16 + quad * 4;
      float vals[4];
#pragma unroll
      for (int r = 0; r < 4; ++r) {
        float v = acc[i][j][r] + bsv;
        if (EPI == EPI_GELU) v = 0.5f * v * (1.0f + erff(v * 0.70710678f));
        if (EPI == EPI_ADDSCALE)
          v = addsrc[(size_t)(row0 + r) * 256 + col] + 0.3f * v;
        vals[r] = v;
      }
      if (VSPLIT && col >= 512) {
        // V: write transposed vt[(b*256 + (col-512))][t], 4 consecutive t
        ushort4 pk;
        pk.x = f2bf(vals[0]); pk.y = f2bf(vals[1]);
        pk.z = f2bf(vals[2]); pk.w = f2bf(vals[3]);
        *(ushort4*)(vt + (size_t)((row0 >> 10) * 256 + (col - 512)) * T_SZ +
                    (row0 & 1023)) = pk;
      } else if (OUTBF) {
#pragma unroll
        for (int r = 0; r < 4; ++r)
          ((u16*)Cv)[(size_t)(row0 + r) * ldc + col_off + col] = f2bf(vals[r]);
      } else {
#pragma unroll
        for (int r = 0; r < 4; ++r)
          ((float*)Cv)[(size_t)(row0 + r) * ldc + col_off + col] = vals[r];
      }
    }
}

// ---------------------------------------------------------------------------
// Fused GEMM (+add) + LayerNorm epilogue, full-occupancy shape:
// BM=16, BN=256 (full row), grid = 512 blocks (2/CU). Wave w owns the 64-col
// slice [w*64, w*64+64); LN row-reduction = wave-local shfl over the 16 ln
// lanes + one small LDS cross-wave combine (single barrier).
// v = addsrc + (A@W^T + bias); y = LN(v) -> outf fp32 (+optional bf16 mirror).
// ---------------------------------------------------------------------------
template <bool WRITE_BF>
__global__ __launch_bounds__(256, 4)
void mgemm_ln16(const u16* __restrict__ A, const u16* __restrict__ Wb, int K,
                const float* __restrict__ bias, const float* __restrict__ addsrc,
                const float* __restrict__ g, const float* __restrict__ bb,
                float* __restrict__ outf, u16* __restrict__ outbf) {
  __shared__ u16 As[2 * 512];     // 2KB: [s][16 rows x 32 k]
  __shared__ u16 Bs[2 * 8192];    // 32KB: [s][16 groups][16 rows x 32 k]
  __shared__ float tS1[4][16], tS2[4][16];
  const int tid = threadIdx.x;
  const int w = tid >> 6, lane = tid & 63;
  const int ln = lane & 15, quad = lane >> 4;
  const int m0 = blockIdx.x * 16;
  const int grow = lane >> 2;      // row within 16-row group
  const int gk8 = (lane & 3) * 8;  // k element offset

  f32x4 acc[4] = {};

  for (int k0 = 0; k0 < K; k0 += 64) {
    // A: wave 0 stages sub-step 0, wave 1 stages sub-step 1
    if (w < 2)
      glds16(A + (size_t)(m0 + grow) * K + k0 + w * 32 + gk8, As + w * 512);
    // B: 32 group-issues (2 sub-steps x 16 groups), 8 per wave
#pragma unroll
    for (int p = 0; p < 8; ++p) {
      const int idx = w * 8 + p;
      const int s = idx >> 4, gg = idx & 15;
      glds16(Wb + (size_t)(gg * 16 + grow) * K + k0 + s * 32 + gk8,
             Bs + s * 8192 + gg * 512);
    }
    __syncthreads();  // drains vmcnt -> LDS valid
#pragma unroll
    for (int s = 0; s < 2; ++s) {
      const bf16x8 af = *(const bf16x8*)(As + s * 512 + ln * 32 + quad * 8);
      const u16* bbase = Bs + s * 8192 + (w * 4) * 512 + ln * 32 + quad * 8;
#pragma unroll
      for (int j = 0; j < 4; ++j) {
        bf16x8 bv = *(const bf16x8*)(bbase + j * 512);
        acc[j] = __builtin_amdgcn_mfma_f32_16x16x32_bf16(af, bv, acc[j], 0, 0, 0);
      }
    }
    __syncthreads();
  }

  // epilogue: add bias + addsrc, accumulate LN stats
  const int row0 = m0 + quad * 4;
  float s1[4] = {}, s2[4] = {};
#pragma unroll
  for (int j = 0; j < 4; ++j) {
    const int col = w * 64 + j * 16 + ln;
    const float bsv = bias[col];
#pragma unroll
    for (int r = 0; r < 4; ++r) {
      float v = acc[j][r] + bsv + addsrc[(size_t)(row0 + r) * 256 + col];
      acc[j][r] = v;
      s1[r] += v;
      s2[r] += v * v;
    }
  }
  // wave-local reduce over the 16 ln lanes (quad = row-parallel)
#pragma unroll
  for (int r = 0; r < 4; ++r) {
#pragma unroll
    for (int o = 8; o > 0; o >>= 1) {
      s1[r] += __shfl_xor(s1[r], o);
      s2[r] += __shfl_xor(s2[r], o);
    }
  }
  if (ln == 0) {
#pragma unroll
    for (int r = 0; r < 4; ++r) {
      tS1[w][quad * 4 + r] = s1[r];
      tS2[w][quad * 4 + r] = s2[r];
    }
  }
  __syncthreads();
  float mean[4], inv[4];
#pragma unroll
  for (int r = 0; r < 4; ++r) {
    const int qr = quad * 4 + r;
    const float S1 = tS1[0][qr] + tS1[1][qr] + tS1[2][qr] + tS1[3][qr];
    const float S2 = tS2[0][qr] + tS2[1][qr] + tS2[2][qr] + tS2[3][qr];
    mean[r] = S1 * (1.f / 256.f);
    const float var = S2 * (1.f / 256.f) - mean[r] * mean[r];
    inv[r] = rsqrtf(var + 1e-5f);
  }
#pragma unroll
  for (int j = 0; j < 4; ++j) {
    const int col = w * 64 + j * 16 + ln;
    const float gc = g[col], bc = bb[col];
#pragma unroll
    for (int r = 0; r < 4; ++r) {
      const float y = (acc[j][r] - mean[r]) * inv[r] * gc + bc;
      outf[(size_t)(row0 + r) * 256 + col] = y;
      if (WRITE_BF) outbf[(size_t)(row0 + r) * 256 + col] = f2bf(y);
    }
  }
}

// ---------------------------------------------------------------------------
// Barrier-free MFMA flash attention (one wave = 16 q rows, paired balance).
// ---------------------------------------------------------------------------
__global__ __launch_bounds__(256)
void attn_flash(const u16* __restrict__ qkv, const u16* __restrict__ vt,
                u16* __restrict__ outp) {
  __shared__ u16 Ps[4][16][72];
  const int tid = threadIdx.x;
  const int w = tid >> 6, lane = tid & 63;
  const int ln = lane & 15, quad = lane >> 4, kq8 = quad * 8;
  const int wu = blockIdx.x * 4 + w;
  const int bh = wu >> 6, s = wu & 63;
  const int qt = (s & 1) ? (63 - (s >> 1)) : (s >> 1);
  const int q0 = qt * 16;
  const int b = bh >> 2, h = bh & 3;
  const u16* base = qkv + (size_t)b * T_SZ * 768;
  const u16* vbase = vt + (size_t)bh * 64 * T_SZ;

  bf16x8 qf[2];
#pragma unroll
  for (int ks = 0; ks < 2; ++ks)
    qf[ks] = *(const bf16x8*)(base + (size_t)(q0 + ln) * 768 + h * 64 +
                              ks * 32 + kq8);
  const short ob = (short)0x3F80;
  const bf16x8 ones = {ob, ob, ob, ob, ob, ob, ob, ob};

  f32x4 O[4] = {};
  f32x4 l_acc = {};
  const int ntiles = (qt >> 2) + 1;
  for (int jt = 0; jt < ntiles; ++jt) {
    const int c0 = jt * 64;
    f32x4 sv[4] = {};
#pragma unroll
    for (int ks = 0; ks < 2; ++ks)
#pragma unroll
      for (int j = 0; j < 4; ++j) {
        bf16x8 kf = *(const bf16x8*)(base + (size_t)(c0 + j * 16 + ln) * 768 +
                                     256 + h * 64 + ks * 32 + kq8);
        sv[j] = __builtin_amdgcn_mfma_f32_16x16x32_bf16(qf[ks], kf, sv[j], 0, 0, 0);
      }
    const bool need_mask = (c0 + 63 > q0);
#pragma unroll
    for (int j = 0; j < 4; ++j)
#pragma unroll
      for (int r = 0; r < 4; ++r) {
        float p = __expf(sv[j][r] * 0.125f);
        if (need_mask && (c0 + j * 16 + ln > q0 + quad * 4 + r)) p = 0.f;
        Ps[w][quad * 4 + r][j * 16 + ln] = f2bf(p);
      }
#pragma unroll
    for (int ks = 0; ks < 2; ++ks) {
      bf16x8 pf = *(const bf16x8*)&Ps[w][ln][ks * 32 + kq8];
      l_acc = __builtin_amdgcn_mfma_f32_16x16x32_bf16(pf, ones, l_acc, 0, 0, 0);
#pragma unroll
      for (int j = 0; j < 4; ++j) {
        bf16x8 vf = *(const bf16x8*)(vbase + (size_t)(j * 16 + ln) * T_SZ +
                                     c0 + ks * 32 + kq8);
        O[j] = __builtin_amdgcn_mfma_f32_16x16x32_bf16(pf, vf, O[j], 0, 0, 0);
      }
    }
  }
  u16* op = outp + (size_t)b * T_SZ * 256;
#pragma unroll
  for (int r = 0; r < 4; ++r) {
    const float inv = 1.f / l_acc[r];
#pragma unroll
    for (int j = 0; j < 4; ++j)
      op[(size_t)(q0 + quad * 4 + r) * 256 + h * 64 + j * 16 + ln] =
          f2bf(O[j][r] * inv);
  }
}

// ---------------------------------------------------------------------------
// block reduction helpers (fp32)
// ---------------------------------------------------------------------------
__device__ __forceinline__ void block_reduce_2(float& a, float& q, float* tmp) {
#pragma unroll
  for (int o = 32; o > 0; o >>= 1) {
    a += __shfl_down(a, o);
    q += __shfl_down(q, o);
  }
  const int lane = threadIdx.x & 63, wid = threadIdx.x >> 6;
  if (lane == 0) { tmp[wid] = a; tmp[4 + wid] = q; }
  __syncthreads();
  a = tmp[0] + tmp[1] + tmp[2] + tmp[3];
  q = tmp[4] + tmp[5] + tmp[6] + tmp[7];
  __syncthreads();
}

__device__ __forceinline__ float ln_finish(float v, float s1, float s2,
                                           float g, float bb) {
  float mean = s1 * (1.f / 256.f);
  float var = s2 * (1.f / 256.f) - mean * mean;
  return (v - mean) * rsqrtf(var + 1e-5f) * g + bb;
}

// ---------------------------------------------------------------------------
// Fused depthwise conv (window 8) + EMA local pass (non-cooperative, 3-kernel
// pipeline as in the 276us baseline).
// ---------------------------------------------------------------------------
__global__ __launch_bounds__(256)
void emaconv_kernel(const float* __restrict__ x, const float* __restrict__ cw,
                    const float* __restrict__ cb, u16* __restrict__ comb,
                    float* __restrict__ scr) {
  const int bc = blockIdx.x;
  const int b = bc >> 5, ch = bc & 31;
  const int d = threadIdx.x;
  const int t0 = ch * 32;
  float wreg[8];
#pragma unroll
  for (int j = 0; j < 8; ++j) wreg[j] = cw[d * 8 + j];
  const float bias = cb[d];
  float xw[8];
#pragma unroll
  for (int j = 0; j < 7; ++j) {
    const int ts = t0 - 7 + j;
    xw[j] = (ts >= 0) ? x[(size_t)(b * T_SZ + ts) * 256 + d] : 0.f;
  }
  float c = 0.f;
#pragma unroll
  for (int tl = 0; tl < 32; ++tl) {
    const size_t row = (size_t)(b * T_SZ + t0 + tl);
    xw[7] = x[row * 256 + d];
    float conv = bias;
#pragma unroll
    for (int j = 0; j < 8; ++j) conv = fmaf(xw[j], wreg[j], conv);
    c = 0.9f * c + 0.1f * xw[7];
    comb[row * 768 + 256 + d] = f2bf(conv);
    comb[row * 768 + 512 + d] = f2bf(c);
#pragma unroll
    for (int j = 0; j < 7; ++j) xw[j] = xw[j + 1];
  }
  scr[(size_t)bc * 256 + d] = c;
}

__global__ __launch_bounds__(256)
void ema_b_kernel(float* __restrict__ scr) {
  const int b = blockIdx.x, d = threadIdx.x;
  const float q32 = 0.03433683820292512f;  // 0.9^32
  float carry = 0.f;
  for (int ch = 0; ch < 32; ++ch) {
    const size_t idx = (size_t)(b * 32 + ch) * 256 + d;
    float e = scr[idx];
    scr[idx] = carry;
    carry = e + q32 * carry;
  }
}

__global__ __launch_bounds__(256)
void ema_c_kernel(u16* __restrict__ comb, const float* __restrict__ scr,
                  float* __restrict__ fts) {
  const int row = blockIdx.x;
  const int b = row >> 10, t = row & 1023;
  const int d = threadIdx.x;
  const int ch = t >> 5, tl = t & 31;
  float carry = scr[(size_t)(b * 32 + ch) * 256 + d];
  float l = bf2f(comb[(size_t)row * 768 + 512 + d]);
  float y = fmaf(__powf(0.9f, (float)(tl + 1)), carry, l);
  comb[(size_t)row * 768 + 512 + d] = f2bf(y);
  if (t == 1023) fts[b * 256 + d] = y;
}

__global__ __launch_bounds__(256)
void cs_a_kernel(float* __restrict__ deltas, float* __restrict__ scr) {
  const int bc = blockIdx.x;
  const int b = bc >> 5, ch = bc & 31;
  const int d = threadIdx.x;
  const int t0 = ch * 32;
  float c = 0.f;
  for (int tl = 0; tl < 32; ++tl) {
    const size_t idx = (size_t)(b * T_SZ + t0 + tl) * 256 + d;
    c += deltas[idx];
    deltas[idx] = c;
  }
  scr[(size_t)bc * 256 + d] = c;
}

__global__ __launch_bounds__(256)
void cs_b_kernel(float* __restrict__ scr) {
  const int b = blockIdx.x, d = threadIdx.x;
  float carry = 0.f;
  for (int ch = 0; ch < 32; ++ch) {
    const size_t idx = (size_t)(b * 32 + ch) * 256 + d;
    float e = scr[idx];
    scr[idx] = carry;
    carry += e;
  }
}

// states = LN3(seq + 0.5*(chunk_cumsum + carry)); the t==1023 block also
// computes fss = LN4(states row) in-place (block-uniform branch).
__global__ __launch_bounds__(256)
void ln3_states_kernel(const float* __restrict__ deltas, const float* __restrict__ scr,
                       const float* __restrict__ seq, const float* __restrict__ g3,
                       const float* __restrict__ b3, const float* __restrict__ g4,
                       const float* __restrict__ b4, u16* __restrict__ st,
                       float* __restrict__ fss) {
  __shared__ float tmp[8];
  const int row = blockIdx.x;
  const int b = row >> 10, t = row & 1023;
  const int d = threadIdx.x;
  float v = seq[b * 256 + d] +
            0.5f * (deltas[(size_t)row * 256 + d] +
                    scr[(size_t)(b * 32 + (t >> 5)) * 256 + d]);
  float a = v, q = v * v;
  block_reduce_2(a, q, tmp);
  const float y = ln_finish(v, a, q, g3[d], b3[d]);
  st[(size_t)row * 256 + d] = f2bf(y);
  if (t == 1023) {
    float a2 = y, q2 = y * y;
    block_reduce_2(a2, q2, tmp);
    fss[b * 256 + d] = ln_finish(y, a2, q2, g4[d], b4[d]);
  }
}

// ---------------------------------------------------------------------------
extern "C" void kernel_launch(void* const* d_in, const int* in_sizes, int n_in,
                              void* d_out, int out_size, void* d_ws,
                              size_t ws_size, hipStream_t stream) {
  (void)in_sizes; (void)n_in; (void)out_size; (void)ws_size;
  const float* parallel_repr = (const float*)d_in[0];
  const float* sequential_state = (const float*)d_in[1];
  const float* in_proj_b = (const float*)d_in[4];
  const float* out_proj_b = (const float*)d_in[6];
  const float* conv_w = (const float*)d_in[7];
  const float* conv_b = (const float*)d_in[8];
  const float* p2s_b = (const float*)d_in[10];
  const float* s2p_b = (const float*)d_in[12];
  const float* trans_b1 = (const float*)d_in[14];
  const float* trans_b2 = (const float*)d_in[16];
  const float* ffn_b1 = (const float*)d_in[18];
  const float* ffn_b2 = (const float*)d_in[20];
  const float* ln1_s = (const float*)d_in[21];
  const float* ln1_b = (const float*)d_in[22];
  const float* ln2_s = (const float*)d_in[23];
  const float* ln2_b = (const float*)d_in[24];
  const float* ln3_s = (const float*)d_in[25];
  const float* ln3_b = (const float*)d_in[26];
  const float* ln4_s = (const float*)d_in[27];
  const float* ln4_b = (const float*)d_in[28];

  char* ws = (char*)d_ws;
  u16* qkv_bf = (u16*)(ws + OFF_QKV);
  u16* attn_bf = (u16*)(ws + OFF_ATTN);
  u16* states_bf = (u16*)(ws + OFF_ATTN);
  u16* f_bf = (u16*)(ws + OFF_F);
  float* x = (float*)(ws + OFF_X);
  u16* comb = (u16*)(ws + OFF_COMB);
  u16* pr_bf = (u16*)(ws + OFF_COMB);  // dead before comb is written
  u16* ffn_in = (u16*)(ws + OFF_COMB); // overlay after comb consumed
  float* fbuf = (float*)(ws + OFF_FB);
  u16* vt = (u16*)(ws + OFF_H);        // dead before h is written
  u16* h_bf = (u16*)(ws + OFF_H);
  u16* x_bf = (u16*)(ws + OFF_XBF);
  u16* wb = (u16*)(ws + OFF_WB);
  float* scr1 = (float*)(ws + OFF_SCR1);
  float* scr2 = (float*)(ws + OFF_SCR2);
  float* out = (float*)d_out;
  float* out_fss = out + S_ELT;
  float* out_fts = out + S_ELT + 2048;

  const dim3 blk(256);

  // 0. weights + parallel_repr -> bf16
  wconv_kernel<<<3456, blk, 0, stream>>>(
      (const float*)d_in[3], (const float*)d_in[5], (const float*)d_in[9],
      (const float*)d_in[11], (const float*)d_in[13], (const float*)d_in[15],
      (const float*)d_in[17], (const float*)d_in[19], parallel_repr, wb, pr_bf);
  // 1. qkv = PR @ in_proj^T + b; V columns written transposed to vt
  mgemm<EPI_NONE, 128, 64, true, true><<<dim3(64, 12), blk, 0, stream>>>(
      pr_bf, 256, wb + WB_INPROJ, 256, in_proj_b, qkv_bf, 768, 0, nullptr, vt);
  // 2. attention (barrier-free)
  attn_flash<<<512, blk, 0, stream>>>(qkv_bf, vt, attn_bf);
  // 3. x = LN1(PR + attn @ out_proj^T + b), fused GEMM+LN -> x fp32 + x_bf
  mgemm_ln16<true><<<512, blk, 0, stream>>>(
      attn_bf, wb + WB_OUTPROJ, 256, out_proj_b, parallel_repr, ln1_s, ln1_b,
      x, x_bf);
  // 4-6. fused conv+EMA -> comb[:,256:768] + traj summary
  emaconv_kernel<<<256, blk, 0, stream>>>(x, conv_w, conv_b, comb, scr1);
  ema_b_kernel<<<8, blk, 0, stream>>>(scr1);
  ema_c_kernel<<<8192, blk, 0, stream>>>(comb, scr1, out_fts);
  // 7. comb[:,0:256] = x + 0.3*(x @ p2s^T + b)
  mgemm<EPI_ADDSCALE, 64, 64, true, false><<<dim3(128, 4), blk, 0, stream>>>(
      x_bf, 256, wb + WB_P2S, 256, p2s_b, comb, 768, 0, x, nullptr);
  // 8. h = gelu(comb @ t1^T + b1)
  mgemm<EPI_GELU, 128, 64, true, false><<<dim3(64, 8), blk, 0, stream>>>(
      comb, 768, wb + WB_T1, 768, trans_b1, h_bf, 512, 0, nullptr, nullptr);
  // 9. deltas = h @ t2^T + b2 -> fbuf (fp32)
  mgemm<EPI_NONE, 64, 64, false, false><<<dim3(128, 4), blk, 0, stream>>>(
      h_bf, 512, wb + WB_T2, 512, trans_b2, fbuf, 256, 0, nullptr, nullptr);
  // 10-11. cumsum
  cs_a_kernel<<<256, blk, 0, stream>>>(fbuf, scr2);
  cs_b_kernel<<<8, blk, 0, stream>>>(scr2);
  // 12. states = LN3(...) -> bf16; t==1023 blocks also emit fss = LN4
  ln3_states_kernel<<<8192, blk, 0, stream>>>(fbuf, scr2, sequential_state,
                                              ln3_s, ln3_b, ln4_s, ln4_b,
                                              states_bf, out_fss);
  // 13. ffn_in = x + 0.3*(states @ s2p^T + b)
  mgemm<EPI_ADDSCALE, 64, 64, true, false><<<dim3(128, 4), blk, 0, stream>>>(
      states_bf, 256, wb + WB_S2P, 256, s2p_b, ffn_in, 256, 0, x, nullptr);
  // 14. f = gelu(ffn_in @ ffn1^T + b1)
  mgemm<EPI_GELU, 128, 64, true, false><<<dim3(64, 16), blk, 0, stream>>>(
      ffn_in, 256, wb + WB_F1, 256, ffn_b1, f_bf, 1024, 0, nullptr, nullptr);
  // 15. out = LN2(x + f @ ffn2^T + b2), fused GEMM+LN
  mgemm_ln16<false><<<512, blk, 0, stream>>>(
      f_bf, wb + WB_F2, 1024, ffn_b2, x, ln2_s, ln2_b, out, nullptr);
}